// Round 4
// baseline (3098.797 us; speedup 1.0000x reference)
//
#include <hip/hip_runtime.h>
#include <stdint.h>

typedef unsigned int uint;

#define B_ 8192
#define D_ 768
#define L_ 16384
#define K_ 32

// ---------------------------------------------------------------------------
// Kernel 0: transpose W [D, L] -> Wt [L, D] so decode reads coalesced rows.
// ---------------------------------------------------------------------------
__global__ __launch_bounds__(256) void transpose_w(
    const float* __restrict__ W, float* __restrict__ Wt)
{
    __shared__ float t[32][33];
    const int bx = blockIdx.x * 32;   // l base
    const int by = blockIdx.y * 32;   // d base
    const int lx = threadIdx.x & 31;
    const int ly4 = (threadIdx.x >> 5) * 4;
    #pragma unroll
    for (int r = 0; r < 4; ++r)
        t[ly4 + r][lx] = W[(size_t)(by + ly4 + r) * L_ + bx + lx];
    __syncthreads();
    #pragma unroll
    for (int r = 0; r < 4; ++r)
        Wt[(size_t)(bx + ly4 + r) * D_ + by + lx] = t[lx][ly4 + r];
}

// ---------------------------------------------------------------------------
// Kernel 1: dense fp32 encode GEMM  z[B,L] = x[B,D] @ W[D,L] + b_enc
// NOTE: each z element is ONE ascending-k fp32 fma chain (single accumulator,
// no reassociation) — bit-matches a BLAS sgemm micro-kernel's accumulation.
// The top-k selection depends on these exact bits; do not reorder.
// ---------------------------------------------------------------------------
__global__ __launch_bounds__(256) void encode_gemm(
    const float* __restrict__ x, const float* __restrict__ W,
    const float* __restrict__ b_enc, float* __restrict__ z)
{
    __shared__ float As[16][128];   // As[k][m]
    __shared__ float Bs[16][128];   // Bs[k][n]

    const int tid = threadIdx.x;
    const int tx = tid & 15, ty = tid >> 4;
    const int m0 = blockIdx.y * 128, n0 = blockIdx.x * 128;
    const int arow = tid >> 1, acol = (tid & 1) * 8;
    const int brow = tid >> 4, bcol = (tid & 15) * 8;

    float acc[8][8];
    #pragma unroll
    for (int i = 0; i < 8; ++i)
        #pragma unroll
        for (int j = 0; j < 8; ++j) acc[i][j] = 0.f;

    const float* xp = x + (size_t)(m0 + arow) * D_;

    for (int k0 = 0; k0 < D_; k0 += 16) {
        float4 a0 = *(const float4*)(xp + k0 + acol);
        float4 a1 = *(const float4*)(xp + k0 + acol + 4);
        const float* wp = W + (size_t)(k0 + brow) * L_ + n0 + bcol;
        float4 b0 = *(const float4*)(wp);
        float4 b1 = *(const float4*)(wp + 4);

        __syncthreads();
        As[acol + 0][arow] = a0.x; As[acol + 1][arow] = a0.y;
        As[acol + 2][arow] = a0.z; As[acol + 3][arow] = a0.w;
        As[acol + 4][arow] = a1.x; As[acol + 5][arow] = a1.y;
        As[acol + 6][arow] = a1.z; As[acol + 7][arow] = a1.w;
        *(float4*)&Bs[brow][bcol]     = b0;
        *(float4*)&Bs[brow][bcol + 4] = b1;
        __syncthreads();

        #pragma unroll
        for (int k = 0; k < 16; ++k) {
            float a[8], b[8];
            *(float4*)&a[0] = *(float4*)&As[k][ty * 8];
            *(float4*)&a[4] = *(float4*)&As[k][ty * 8 + 4];
            *(float4*)&b[0] = *(float4*)&Bs[k][tx * 8];
            *(float4*)&b[4] = *(float4*)&Bs[k][tx * 8 + 4];
            #pragma unroll
            for (int i = 0; i < 8; ++i)
                #pragma unroll
                for (int j = 0; j < 8; ++j)
                    acc[i][j] = fmaf(a[i], b[j], acc[i][j]);
        }
    }

    float4 be0 = *(const float4*)&b_enc[n0 + tx * 8];
    float4 be1 = *(const float4*)&b_enc[n0 + tx * 8 + 4];
    #pragma unroll
    for (int i = 0; i < 8; ++i) {
        size_t off = (size_t)(m0 + ty * 8 + i) * L_ + n0 + tx * 8;
        float4 o0 = make_float4(acc[i][0] + be0.x, acc[i][1] + be0.y,
                                acc[i][2] + be0.z, acc[i][3] + be0.w);
        float4 o1 = make_float4(acc[i][4] + be1.x, acc[i][5] + be1.y,
                                acc[i][6] + be1.z, acc[i][7] + be1.w);
        *(float4*)(z + off)     = o0;
        *(float4*)(z + off + 4) = o1;
    }
}

// ---------------------------------------------------------------------------
// Kernel 2: per-row top-32 PURELY ON z's fp32 BITS (no refine). Full 31-bit
// radix search finds the exact rank-32 |z| bit pattern T; select |z| > T plus
// the lowest-index elements among exact ties at T (jax top_k tie semantics).
// Then in-place sparsify of z and sparse decode.
// ---------------------------------------------------------------------------
__global__ __launch_bounds__(256) void topk_decode(
    const float* __restrict__ W, const float* __restrict__ Wt,
    const float* __restrict__ b_dec, float* __restrict__ zbuf,
    float* __restrict__ recon, int use_t)
{
    __shared__ uint  flags[L_ / 32];
    __shared__ int   tie_l[64];
    __shared__ int   tie_sel[64];
    __shared__ int   sel_l[64];
    __shared__ float sel_v[64];
    __shared__ int   s_ntie, s_nsel;
    __shared__ int   s_cnt[8];

    const int tid  = threadIdx.x;
    const int lane = tid & 63, wv = tid >> 6;
    const int row  = blockIdx.x;

    float* zrow = zbuf + (size_t)row * L_;
    float4 zr[16];
    #pragma unroll
    for (int s = 0; s < 16; ++s) zr[s] = ((const float4*)zrow)[tid + s * 256];

    if (tid == 0) { s_ntie = 0; s_nsel = 0; }
    if (tid < 64) tie_sel[tid] = 0;
    #pragma unroll
    for (int i = 0; i < 2; ++i) flags[tid + i * 256] = 0u;
    __syncthreads();

    // ---- full radix search (bits 30..0) for the exact rank-32 |z| pattern ----
    uint t = 0;
    for (int bit = 30; bit >= 0; --bit) {
        float tf = __uint_as_float(t | (1u << bit));
        int cnt = 0;
        #pragma unroll
        for (int s = 0; s < 16; ++s) {
            cnt += (fabsf(zr[s].x) >= tf);
            cnt += (fabsf(zr[s].y) >= tf);
            cnt += (fabsf(zr[s].z) >= tf);
            cnt += (fabsf(zr[s].w) >= tf);
        }
        #pragma unroll
        for (int off = 32; off; off >>= 1) cnt += __shfl_down(cnt, off);
        int half = (bit & 1) << 2;
        if (lane == 0) s_cnt[half | wv] = cnt;
        __syncthreads();
        int total = s_cnt[half] + s_cnt[half + 1] + s_cnt[half + 2] + s_cnt[half + 3];
        if (total >= K_) t |= (1u << bit);
    }
    // Now count(|z| >= T) >= 32 and count(|z| >= T+1ulp) < 32 ⇒ T is the
    // exact bit pattern of the rank-32 value (at least one element equals T).
    const float Tf = __uint_as_float(t);

    // ---- strictly-greater count (these are certainly selected) ----
    {
        int cnt = 0;
        #pragma unroll
        for (int s = 0; s < 16; ++s) {
            cnt += (fabsf(zr[s].x) > Tf);
            cnt += (fabsf(zr[s].y) > Tf);
            cnt += (fabsf(zr[s].z) > Tf);
            cnt += (fabsf(zr[s].w) > Tf);
        }
        #pragma unroll
        for (int off = 32; off; off >>= 1) cnt += __shfl_down(cnt, off);
        if (lane == 0) s_cnt[4 | wv] = cnt;   // parity-1 slots; safe per barrier order
    }
    __syncthreads();
    const int cntGT = s_cnt[4] + s_cnt[5] + s_cnt[6] + s_cnt[7];
    const int need  = K_ - cntGT;   // >= 1 by radix invariant

    // ---- gather exact ties at T ----
    #define TIEG(comp, idx)                                                \
        { if (fabsf(comp) == Tf) {                                         \
              int p_ = atomicAdd(&s_ntie, 1);                              \
              if (p_ < 64) tie_l[p_] = (idx); } }
    #pragma unroll
    for (int s = 0; s < 16; ++s) {
        int j = (tid + s * 256) * 4;
        TIEG(zr[s].x, j + 0)
        TIEG(zr[s].y, j + 1)
        TIEG(zr[s].z, j + 2)
        TIEG(zr[s].w, j + 3)
    }
    #undef TIEG
    __syncthreads();

    int nt = min(s_ntie, 64);
    if (tid == 0) {
        for (int n = 0; n < need && n < nt; ++n) {   // lowest indices win
            int best = -1, bl = 0x7fffffff;
            for (int c = 0; c < nt; ++c)
                if (!tie_sel[c] && tie_l[c] < bl) { bl = tie_l[c]; best = c; }
            tie_sel[best] = 1;
        }
    }
    __syncthreads();

    // ---- selection bitmap: strictly greater + selected ties ----
    #define FLAGC(comp, idx)                                               \
        { if (fabsf(comp) > Tf)                                            \
              atomicOr(&flags[(idx) >> 5], 1u << ((idx) & 31)); }
    #pragma unroll
    for (int s = 0; s < 16; ++s) {
        int j = (tid + s * 256) * 4;
        FLAGC(zr[s].x, j + 0)
        FLAGC(zr[s].y, j + 1)
        FLAGC(zr[s].z, j + 2)
        FLAGC(zr[s].w, j + 3)
    }
    #undef FLAGC
    if (tid < nt && tie_sel[tid]) {
        int j = tie_l[tid];
        atomicOr(&flags[j >> 5], 1u << (j & 31));
    }
    __syncthreads();

    // ---- masked write-back (in place) + gather selected (l, value) ----
    #pragma unroll
    for (int s = 0; s < 16; ++s) {
        int q = tid + s * 256;
        int j = q * 4;
        uint f = flags[j >> 5] >> (j & 31);
        float4 v = zr[s];
        if (f & 15u) {
            if (f & 1u) { int p = atomicAdd(&s_nsel, 1); if (p < 64) { sel_l[p] = j;     sel_v[p] = v.x; } }
            if (f & 2u) { int p = atomicAdd(&s_nsel, 1); if (p < 64) { sel_l[p] = j + 1; sel_v[p] = v.y; } }
            if (f & 4u) { int p = atomicAdd(&s_nsel, 1); if (p < 64) { sel_l[p] = j + 2; sel_v[p] = v.z; } }
            if (f & 8u) { int p = atomicAdd(&s_nsel, 1); if (p < 64) { sel_l[p] = j + 3; sel_v[p] = v.w; } }
        }
        v.x = (f & 1u) ? v.x : 0.f;
        v.y = (f & 2u) ? v.y : 0.f;
        v.z = (f & 4u) ? v.z : 0.f;
        v.w = (f & 8u) ? v.w : 0.f;
        ((float4*)zrow)[q] = v;
    }
    __syncthreads();

    // ---- sparse decode: recon[row,:] = sum_k sel_v[k] * W[:, sel_l[k]] + b_dec ----
    int ns = min(s_nsel, 64);
    if (use_t) {
        #pragma unroll
        for (int i = 0; i < 3; ++i) {
            int d = tid + i * 256;
            float acc = b_dec[d];
            for (int c = 0; c < ns; ++c)
                acc = fmaf(sel_v[c], Wt[(size_t)sel_l[c] * D_ + d], acc);
            recon[(size_t)row * D_ + d] = acc;
        }
    } else {
        #pragma unroll
        for (int i = 0; i < 3; ++i) {
            int d = tid + i * 256;
            float acc = b_dec[d];
            for (int c = 0; c < ns; ++c)
                acc = fmaf(sel_v[c], W[(size_t)d * L_ + sel_l[c]], acc);
            recon[(size_t)row * D_ + d] = acc;
        }
    }
}

// ---------------------------------------------------------------------------
extern "C" void kernel_launch(void* const* d_in, const int* in_sizes, int n_in,
                              void* d_out, int out_size, void* d_ws, size_t ws_size,
                              hipStream_t stream)
{
    const float* x     = (const float*)d_in[0];
    const float* W     = (const float*)d_in[1];
    const float* b_enc = (const float*)d_in[2];
    const float* b_dec = (const float*)d_in[3];

    float* recon = (float*)d_out;                  // [B, D]
    float* z     = recon + (size_t)B_ * D_;        // [B, L] (dense z, then z_sparse)
    float* Wt    = (float*)d_ws;                   // [L, D] transposed W
    int use_t    = ws_size >= (size_t)L_ * D_ * sizeof(float);

    if (use_t) {
        dim3 gt(L_ / 32, D_ / 32);
        transpose_w<<<gt, 256, 0, stream>>>(W, Wt);
    }
    dim3 g1(L_ / 128, B_ / 128);
    encode_gemm<<<g1, 256, 0, stream>>>(x, W, b_enc, z);
    topk_decode<<<B_, 256, 0, stream>>>(W, Wt, b_dec, z, recon, use_t);
}

// Round 5
// 1707.857 us; speedup vs baseline: 1.8144x; 1.8144x over previous
//
#include <hip/hip_runtime.h>
#include <stdint.h>

typedef unsigned int uint;
typedef unsigned short ushort;

#define B_ 8192
#define D_ 768
#define L_ 16384
#define K_ 32
#define KC_ 24          // 768 / 32 K-chunks
#define NCAND 64
#define M_WIN 1e-3f     // boundary ambiguity window (>= 2x worst |z_a - z_e|)

typedef __attribute__((ext_vector_type(8))) short short8;
typedef __attribute__((ext_vector_type(4))) float f32x4;

__device__ __forceinline__ void glds16(const void* g, void* l) {
    __builtin_amdgcn_global_load_lds((const __attribute__((address_space(1))) void*)g,
                                     (__attribute__((address_space(3))) void*)l, 16, 0, 0);
}

// ---------------------------------------------------------------------------
// Kernel 0: transpose W [D, L] -> Wt [L, D] (fp32, for coalesced decode).
// ---------------------------------------------------------------------------
__global__ __launch_bounds__(256) void transpose_w(
    const float* __restrict__ W, float* __restrict__ Wt)
{
    __shared__ float t[32][33];
    const int bx = blockIdx.x * 32, by = blockIdx.y * 32;
    const int lx = threadIdx.x & 31;
    const int ly4 = (threadIdx.x >> 5) * 4;
    #pragma unroll
    for (int r = 0; r < 4; ++r)
        t[ly4 + r][lx] = W[(size_t)(by + ly4 + r) * L_ + bx + lx];
    __syncthreads();
    #pragma unroll
    for (int r = 0; r < 4; ++r)
        Wt[(size_t)(bx + ly4 + r) * D_ + by + lx] = t[lx][ly4 + r];
}

// ---------------------------------------------------------------------------
// bf16 hi/lo split helpers (truncation — exact residual, no rounding modes).
// ---------------------------------------------------------------------------
__device__ __forceinline__ void split8(const float* f, uint4* H, uint4* Lo) {
    ushort hs[8], ls[8];
    #pragma unroll
    for (int j = 0; j < 8; ++j) {
        uint ub = __float_as_uint(f[j]);
        hs[j] = (ushort)(ub >> 16);
        float hf = __uint_as_float((uint)hs[j] << 16);
        float r = f[j] - hf;                   // exact
        ls[j] = (ushort)(__float_as_uint(r) >> 16);
    }
    *H  = make_uint4(hs[0] | (uint)hs[1] << 16, hs[2] | (uint)hs[3] << 16,
                     hs[4] | (uint)hs[5] << 16, hs[6] | (uint)hs[7] << 16);
    *Lo = make_uint4(ls[0] | (uint)ls[1] << 16, ls[2] | (uint)ls[3] << 16,
                     ls[4] | (uint)ls[5] << 16, ls[6] | (uint)ls[7] << 16);
}

// ---------------------------------------------------------------------------
// Kernel P1: pack x [B,D] fp32 -> Ah, Al bf16 in MFMA-fragment order:
// chunk(mb,kc)[mtile(8)][q(4)][m(16)][j(8)], elem = x[mb*128+mtile*16+m][kc*32+q*8+j]
// ---------------------------------------------------------------------------
__global__ __launch_bounds__(256) void pack_x(
    const float* __restrict__ x, ushort* __restrict__ Ah, ushort* __restrict__ Al)
{
    const int c = blockIdx.x;            // (mb, kc)
    const int mb = c / KC_, kc = c % KC_;
    const size_t cbase = (size_t)c * 4096;
    #pragma unroll
    for (int h = 0; h < 2; ++h) {
        int u = threadIdx.x + h * 256;   // unit: mtile*64 + q*16 + m
        int mtile = u >> 6, q = (u >> 4) & 3, m = u & 15;
        int row = mb * 128 + mtile * 16 + m;
        int k0 = kc * 32 + q * 8;
        float f[8];
        *(float4*)&f[0] = *(const float4*)(x + (size_t)row * D_ + k0);
        *(float4*)&f[4] = *(const float4*)(x + (size_t)row * D_ + k0 + 4);
        uint4 H, Lo;
        split8(f, &H, &Lo);
        *(uint4*)(Ah + cbase + (size_t)u * 8) = H;
        *(uint4*)(Al + cbase + (size_t)u * 8) = Lo;
    }
}

// ---------------------------------------------------------------------------
// Kernel P2: pack W [D,L] fp32 -> Bh, Bl bf16 in MFMA-fragment order:
// chunk(nb,kc)[ntile(8)][q(4)][n(16)][j(8)], elem = W[kc*32+q*8+j][nb*128+ntile*16+n]
// ---------------------------------------------------------------------------
__global__ __launch_bounds__(256) void pack_w(
    const float* __restrict__ W, ushort* __restrict__ Bh, ushort* __restrict__ Bl)
{
    const int c = blockIdx.x;            // (nb, kc)
    const int nb = c / KC_, kc = c % KC_;
    const size_t cbase = (size_t)c * 4096;
    #pragma unroll
    for (int h = 0; h < 2; ++h) {
        int u = threadIdx.x + h * 256;   // unit: ntile*64 + q*16 + n
        int ntile = u >> 6, q = (u >> 4) & 3, n = u & 15;
        int col = nb * 128 + ntile * 16 + n;
        int k0 = kc * 32 + q * 8;
        float f[8];
        #pragma unroll
        for (int j = 0; j < 8; ++j)
            f[j] = W[(size_t)(k0 + j) * L_ + col];
        uint4 H, Lo;
        split8(f, &H, &Lo);
        *(uint4*)(Bh + cbase + (size_t)u * 8) = H;
        *(uint4*)(Bl + cbase + (size_t)u * 8) = Lo;
    }
}

// ---------------------------------------------------------------------------
// Kernel 1-fast: bf16-split MFMA encode. z = (Ah+Al)(Bh+Bl) ~= AhBh+AhBl+AlBh.
// 128x128 tile, BK=32, 4 waves (2x2 of 64x64), 16x16x32 MFMA, global_load_lds.
// ---------------------------------------------------------------------------
__global__ __launch_bounds__(256) void encode_mfma(
    const ushort* __restrict__ Ah, const ushort* __restrict__ Al,
    const ushort* __restrict__ Bh, const ushort* __restrict__ Bl,
    const float* __restrict__ b_enc, float* __restrict__ z)
{
    __shared__ ushort sAh[4096], sAl[4096], sBh[4096], sBl[4096];  // 8 KB each

    const int tid = threadIdx.x;
    const int lane = tid & 63, w = tid >> 6;
    const int wr = w >> 1, wc = w & 1;
    const int mb = blockIdx.x, nb = blockIdx.y;   // consecutive blocks share nb-range locality via dispatch

    f32x4 acc[4][4];
    #pragma unroll
    for (int i = 0; i < 4; ++i)
        #pragma unroll
        for (int j = 0; j < 4; ++j) acc[i][j] = (f32x4){0.f, 0.f, 0.f, 0.f};

    for (int kc = 0; kc < KC_; ++kc) {
        const size_t ca = ((size_t)(mb * KC_ + kc)) * 4096;
        const size_t cb = ((size_t)(nb * KC_ + kc)) * 4096;
        // stage 4x8KB via global_load_lds: per wave 2 KB per operand (2 x 1KB instrs)
        #pragma unroll
        for (int i = 0; i < 2; ++i) {
            int off = w * 1024 + i * 512 + lane * 8;   // ushort units
            int ldo = w * 1024 + i * 512;
            glds16(Ah + ca + off, &sAh[ldo]);
            glds16(Al + ca + off, &sAl[ldo]);
            glds16(Bh + cb + off, &sBh[ldo]);
            glds16(Bl + cb + off, &sBl[ldo]);
        }
        asm volatile("s_waitcnt vmcnt(0)" ::: "memory");
        __syncthreads();

        short8 fAh[4], fAl[4], fBh[4], fBl[4];
        #pragma unroll
        for (int i = 0; i < 4; ++i) {
            int mt = wr * 4 + i;
            fAh[i] = *(const short8*)&sAh[mt * 512 + lane * 8];
            fAl[i] = *(const short8*)&sAl[mt * 512 + lane * 8];
        }
        #pragma unroll
        for (int j = 0; j < 4; ++j) {
            int nt = wc * 4 + j;
            fBh[j] = *(const short8*)&sBh[nt * 512 + lane * 8];
            fBl[j] = *(const short8*)&sBl[nt * 512 + lane * 8];
        }
        #pragma unroll
        for (int i = 0; i < 4; ++i)
            #pragma unroll
            for (int j = 0; j < 4; ++j) {
                acc[i][j] = __builtin_amdgcn_mfma_f32_16x16x32_bf16(fAh[i], fBh[j], acc[i][j], 0, 0, 0);
                acc[i][j] = __builtin_amdgcn_mfma_f32_16x16x32_bf16(fAh[i], fBl[j], acc[i][j], 0, 0, 0);
                acc[i][j] = __builtin_amdgcn_mfma_f32_16x16x32_bf16(fAl[i], fBh[j], acc[i][j], 0, 0, 0);
            }
        __syncthreads();
    }

    // epilogue: C/D layout col=lane&15, row=(lane>>4)*4+reg  [verified m89/m91]
    const int q = lane >> 4, cb16 = lane & 15;
    #pragma unroll
    for (int j = 0; j < 4; ++j) {
        int col = nb * 128 + (wc * 4 + j) * 16 + cb16;
        float be = b_enc[col];
        #pragma unroll
        for (int i = 0; i < 4; ++i) {
            int rb = mb * 128 + (wr * 4 + i) * 16 + q * 4;
            #pragma unroll
            for (int r = 0; r < 4; ++r)
                z[(size_t)(rb + r) * L_ + col] = acc[i][j][r] + be;
        }
    }
}

// ---------------------------------------------------------------------------
// Kernel 1-fallback: exact fp32 encode (round-4 proven; reference-bit chain).
// ---------------------------------------------------------------------------
__global__ __launch_bounds__(256) void encode_gemm(
    const float* __restrict__ x, const float* __restrict__ W,
    const float* __restrict__ b_enc, float* __restrict__ z)
{
    __shared__ float As[16][128];
    __shared__ float Bs[16][128];

    const int tid = threadIdx.x;
    const int tx = tid & 15, ty = tid >> 4;
    const int m0 = blockIdx.y * 128, n0 = blockIdx.x * 128;
    const int arow = tid >> 1, acol = (tid & 1) * 8;
    const int brow = tid >> 4, bcol = (tid & 15) * 8;

    float acc[8][8];
    #pragma unroll
    for (int i = 0; i < 8; ++i)
        #pragma unroll
        for (int j = 0; j < 8; ++j) acc[i][j] = 0.f;

    const float* xp = x + (size_t)(m0 + arow) * D_;

    for (int k0 = 0; k0 < D_; k0 += 16) {
        float4 a0 = *(const float4*)(xp + k0 + acol);
        float4 a1 = *(const float4*)(xp + k0 + acol + 4);
        const float* wp = W + (size_t)(k0 + brow) * L_ + n0 + bcol;
        float4 b0 = *(const float4*)(wp);
        float4 b1 = *(const float4*)(wp + 4);

        __syncthreads();
        As[acol + 0][arow] = a0.x; As[acol + 1][arow] = a0.y;
        As[acol + 2][arow] = a0.z; As[acol + 3][arow] = a0.w;
        As[acol + 4][arow] = a1.x; As[acol + 5][arow] = a1.y;
        As[acol + 6][arow] = a1.z; As[acol + 7][arow] = a1.w;
        *(float4*)&Bs[brow][bcol]     = b0;
        *(float4*)&Bs[brow][bcol + 4] = b1;
        __syncthreads();

        #pragma unroll
        for (int k = 0; k < 16; ++k) {
            float a[8], b[8];
            *(float4*)&a[0] = *(float4*)&As[k][ty * 8];
            *(float4*)&a[4] = *(float4*)&As[k][ty * 8 + 4];
            *(float4*)&b[0] = *(float4*)&Bs[k][tx * 8];
            *(float4*)&b[4] = *(float4*)&Bs[k][tx * 8 + 4];
            #pragma unroll
            for (int i = 0; i < 8; ++i)
                #pragma unroll
                for (int j = 0; j < 8; ++j)
                    acc[i][j] = fmaf(a[i], b[j], acc[i][j]);
        }
    }

    float4 be0 = *(const float4*)&b_enc[n0 + tx * 8];
    float4 be1 = *(const float4*)&b_enc[n0 + tx * 8 + 4];
    #pragma unroll
    for (int i = 0; i < 8; ++i) {
        size_t off = (size_t)(m0 + ty * 8 + i) * L_ + n0 + tx * 8;
        *(float4*)(z + off)     = make_float4(acc[i][0] + be0.x, acc[i][1] + be0.y,
                                              acc[i][2] + be0.z, acc[i][3] + be0.w);
        *(float4*)(z + off + 4) = make_float4(acc[i][4] + be1.x, acc[i][5] + be1.y,
                                              acc[i][6] + be1.z, acc[i][7] + be1.w);
    }
}

// ---------------------------------------------------------------------------
// Kernel 2: per-row top-32 on z_a with exact-chain replay for the ambiguity
// window (reference semantics: fp32 ascending-k fma bits, lowest-index ties).
// ---------------------------------------------------------------------------
__global__ __launch_bounds__(256) void topk_decode(
    const float* __restrict__ x, const float* __restrict__ W,
    const float* __restrict__ Wt, const float* __restrict__ b_enc,
    const float* __restrict__ b_dec, float* __restrict__ zbuf,
    float* __restrict__ recon, int use_t)
{
    __shared__ uint  flags[L_ / 32];
    __shared__ float xs[D_];
    __shared__ float wcol[8][D_];
    __shared__ int   cand_l[NCAND];
    __shared__ float cand_e[NCAND];
    __shared__ int   selflag[NCAND];
    __shared__ int   sel_l[64];
    __shared__ float sel_v[64];
    __shared__ int   s_ncand, s_nsel;
    __shared__ int   s_cnt[8];

    const int tid  = threadIdx.x;
    const int lane = tid & 63, wv = tid >> 6;
    const int row  = blockIdx.x;

    float* zrow = zbuf + (size_t)row * L_;
    float4 zr[16];
    #pragma unroll
    for (int s = 0; s < 16; ++s) zr[s] = ((const float4*)zrow)[tid + s * 256];

    if (tid == 0) { s_ncand = 0; s_nsel = 0; }
    if (tid < NCAND) selflag[tid] = 0;
    #pragma unroll
    for (int i = 0; i < 2; ++i) flags[tid + i * 256] = 0u;
    __syncthreads();

    // ---- radix search (bits 30..0) for rank-32 |z_a| bit pattern ----
    uint t = 0;
    for (int bit = 30; bit >= 0; --bit) {
        float tf = __uint_as_float(t | (1u << bit));
        int cnt = 0;
        #pragma unroll
        for (int s = 0; s < 16; ++s) {
            cnt += (fabsf(zr[s].x) >= tf);
            cnt += (fabsf(zr[s].y) >= tf);
            cnt += (fabsf(zr[s].z) >= tf);
            cnt += (fabsf(zr[s].w) >= tf);
        }
        #pragma unroll
        for (int off = 32; off; off >>= 1) cnt += __shfl_down(cnt, off);
        int half = (bit & 1) << 2;
        if (lane == 0) s_cnt[half | wv] = cnt;
        __syncthreads();
        int total = s_cnt[half] + s_cnt[half + 1] + s_cnt[half + 2] + s_cnt[half + 3];
        if (total >= K_) t |= (1u << bit);
    }
    const float Tf = __uint_as_float(t);
    const float hi_thr = Tf + M_WIN;
    const float lo_thr = Tf - M_WIN;

    // ---- strictly-above-window count (certainly in exact top-32) ----
    {
        int cnt = 0;
        #pragma unroll
        for (int s = 0; s < 16; ++s) {
            cnt += (fabsf(zr[s].x) > hi_thr);
            cnt += (fabsf(zr[s].y) > hi_thr);
            cnt += (fabsf(zr[s].z) > hi_thr);
            cnt += (fabsf(zr[s].w) > hi_thr);
        }
        #pragma unroll
        for (int off = 32; off; off >>= 1) cnt += __shfl_down(cnt, off);
        if (lane == 0) s_cnt[4 | wv] = cnt;
    }
    // ---- gather window candidates ----
    #define GATHER(comp, idx)                                              \
        { float az_ = fabsf(comp);                                         \
          if (az_ >= lo_thr && az_ <= hi_thr) {                            \
              int p_ = atomicAdd(&s_ncand, 1);                             \
              if (p_ < NCAND) cand_l[p_] = (idx); } }
    #pragma unroll
    for (int s = 0; s < 16; ++s) {
        int j = (tid + s * 256) * 4;
        GATHER(zr[s].x, j + 0)
        GATHER(zr[s].y, j + 1)
        GATHER(zr[s].z, j + 2)
        GATHER(zr[s].w, j + 3)
    }
    #undef GATHER
    __syncthreads();

    const int cntGT = s_cnt[4] + s_cnt[5] + s_cnt[6] + s_cnt[7];
    const int need  = K_ - cntGT;            // >= 1 by radix invariant
    const int nc    = min(s_ncand, NCAND);   // >= need

    if (nc > need) {
        // ---- replay exact fp32 ascending-k chains for candidates ----
        #pragma unroll
        for (int i = 0; i < 3; ++i)
            xs[tid + i * 256] = x[(size_t)row * D_ + tid + i * 256];
        __syncthreads();
        for (int g = 0; g < nc; g += 8) {
            int ng = min(8, nc - g);
            for (int cc = 0; cc < ng; ++cc) {
                int l = cand_l[g + cc];
                #pragma unroll
                for (int i = 0; i < 3; ++i)
                    wcol[cc][tid + i * 256] = W[(size_t)(tid + i * 256) * L_ + l];
            }
            __syncthreads();
            if (tid < ng) {
                int c = g + tid;
                float a = 0.f;
                for (int k = 0; k < D_; ++k)
                    a = fmaf(xs[k], wcol[tid][k], a);     // exact reference chain
                cand_e[c] = fabsf(a + b_enc[cand_l[c]]);
            }
            __syncthreads();
        }
    }
    __syncthreads();

    if (tid == 0) {
        if (nc <= need) {
            for (int c = 0; c < nc; ++c) selflag[c] = 1;
        } else {
            for (int itn = 0; itn < need; ++itn) {   // exact desc, idx asc
                int best = -1; float bv = -1.f; int bl = 0x7fffffff;
                for (int c = 0; c < nc; ++c) {
                    if (selflag[c]) continue;
                    float v = cand_e[c]; int l = cand_l[c];
                    if (v > bv || (v == bv && l < bl)) { best = c; bv = v; bl = l; }
                }
                selflag[best] = 1;
            }
        }
    }
    __syncthreads();

    // ---- selection bitmap: certain + selected candidates ----
    #define FLAGC(comp, idx)                                               \
        { if (fabsf(comp) > hi_thr)                                        \
              atomicOr(&flags[(idx) >> 5], 1u << ((idx) & 31)); }
    #pragma unroll
    for (int s = 0; s < 16; ++s) {
        int j = (tid + s * 256) * 4;
        FLAGC(zr[s].x, j + 0)
        FLAGC(zr[s].y, j + 1)
        FLAGC(zr[s].z, j + 2)
        FLAGC(zr[s].w, j + 3)
    }
    #undef FLAGC
    if (tid < nc && selflag[tid]) {
        int j = cand_l[tid];
        atomicOr(&flags[j >> 5], 1u << (j & 31));
    }
    __syncthreads();

    // ---- masked write-back (in place) + gather selected (l, value) ----
    #pragma unroll
    for (int s = 0; s < 16; ++s) {
        int q = tid + s * 256;
        int j = q * 4;
        uint f = flags[j >> 5] >> (j & 31);
        float4 v = zr[s];
        if (f & 15u) {
            if (f & 1u) { int p = atomicAdd(&s_nsel, 1); if (p < 64) { sel_l[p] = j;     sel_v[p] = v.x; } }
            if (f & 2u) { int p = atomicAdd(&s_nsel, 1); if (p < 64) { sel_l[p] = j + 1; sel_v[p] = v.y; } }
            if (f & 4u) { int p = atomicAdd(&s_nsel, 1); if (p < 64) { sel_l[p] = j + 2; sel_v[p] = v.z; } }
            if (f & 8u) { int p = atomicAdd(&s_nsel, 1); if (p < 64) { sel_l[p] = j + 3; sel_v[p] = v.w; } }
        }
        v.x = (f & 1u) ? v.x : 0.f;
        v.y = (f & 2u) ? v.y : 0.f;
        v.z = (f & 4u) ? v.z : 0.f;
        v.w = (f & 8u) ? v.w : 0.f;
        ((float4*)zrow)[q] = v;
    }
    __syncthreads();

    // ---- sparse decode ----
    int ns = min(s_nsel, 64);
    if (use_t) {
        #pragma unroll
        for (int i = 0; i < 3; ++i) {
            int d = tid + i * 256;
            float acc = b_dec[d];
            for (int c = 0; c < ns; ++c)
                acc = fmaf(sel_v[c], Wt[(size_t)sel_l[c] * D_ + d], acc);
            recon[(size_t)row * D_ + d] = acc;
        }
    } else {
        #pragma unroll
        for (int i = 0; i < 3; ++i) {
            int d = tid + i * 256;
            float acc = b_dec[d];
            for (int c = 0; c < ns; ++c)
                acc = fmaf(sel_v[c], W[(size_t)d * L_ + sel_l[c]], acc);
            recon[(size_t)row * D_ + d] = acc;
        }
    }
}

// ---------------------------------------------------------------------------
extern "C" void kernel_launch(void* const* d_in, const int* in_sizes, int n_in,
                              void* d_out, int out_size, void* d_ws, size_t ws_size,
                              hipStream_t stream)
{
    const float* x     = (const float*)d_in[0];
    const float* W     = (const float*)d_in[1];
    const float* b_enc = (const float*)d_in[2];
    const float* b_dec = (const float*)d_in[3];

    float* recon = (float*)d_out;                  // [B, D]
    float* z     = recon + (size_t)B_ * D_;        // [B, L] (z, then z_sparse in place)

    const size_t wt_b = (size_t)L_ * D_ * 4;       // 50.3 MB
    const size_t ah_b = (size_t)B_ * D_ * 2;       // 12.6 MB
    const size_t bh_b = (size_t)D_ * L_ * 2;       // 25.2 MB
    const size_t need_fast = wt_b + 2 * ah_b + 2 * bh_b;

    float*  Wt = (float*)d_ws;
    ushort* Ah = (ushort*)((char*)d_ws + wt_b);
    ushort* Al = (ushort*)((char*)d_ws + wt_b + ah_b);
    ushort* Bh = (ushort*)((char*)d_ws + wt_b + 2 * ah_b);
    ushort* Bl = (ushort*)((char*)d_ws + wt_b + 2 * ah_b + bh_b);

    const int use_t = ws_size >= wt_b;
    const int fast  = ws_size >= need_fast;

    if (use_t) {
        dim3 gt(L_ / 32, D_ / 32);
        transpose_w<<<gt, 256, 0, stream>>>(W, Wt);
    }
    if (fast) {
        pack_x<<<(B_ / 128) * KC_, 256, 0, stream>>>(x, Ah, Al);
        pack_w<<<(L_ / 128) * KC_, 256, 0, stream>>>(W, Bh, Bl);
        dim3 g1(B_ / 128, L_ / 128);
        encode_mfma<<<g1, 256, 0, stream>>>(Ah, Al, Bh, Bl, b_enc, z);
    } else {
        dim3 g1(L_ / 128, B_ / 128);
        encode_gemm<<<g1, 256, 0, stream>>>(x, W, b_enc, z);
    }
    topk_decode<<<B_, 256, 0, stream>>>(x, W, Wt, b_enc, b_dec, z, recon, use_t);
}